// Round 1
// baseline (399.320 us; speedup 1.0000x reference)
//
#include <hip/hip_runtime.h>
#include <hip/hip_bf16.h>

#define DEVI static __device__ __forceinline__

typedef __attribute__((ext_vector_type(8))) short bf16x8;
typedef __attribute__((ext_vector_type(4))) float f32x4;
typedef __attribute__((ext_vector_type(4))) int i32x4;
typedef __attribute__((ext_vector_type(2))) unsigned u32x2;

constexpr int NE = 8;
constexpr int HID = 1024;
constexpr int INTER = 2048;
constexpr int BM = 128, BN = 128, BK = 64;

// LDS layout: [row][BK] bf16, XOR-swizzled: element index ^ ((r&7)<<3)
// (byte ^ ((r&7)<<4)) -> breaks the 128B-row same-bank column on ds_read_b128.
DEVI int swz(int r, int c) { return (r * BK + c) ^ ((r & 7) << 3); }

DEVI short f2bf(float f) {
  union { float f; unsigned u; } v;
  v.f = f;
  unsigned r = v.u + 0x7FFFu + ((v.u >> 16) & 1u);  // round-to-nearest-even
  return (short)(r >> 16);
}

DEVI u32x2 pack4(float a, float b, float c, float d) {
  u32x2 o;
  o[0] = (unsigned)(unsigned short)f2bf(a) | ((unsigned)(unsigned short)f2bf(b) << 16);
  o[1] = (unsigned)(unsigned short)f2bf(c) | ((unsigned)(unsigned short)f2bf(d) << 16);
  return o;
}

// Stage activation tile (fp32 source, k-contiguous) -> LDS [128][64] bf16 swizzled
DEVI void stage_a_f32(short* As, const float* src, int ldA, int row_lim, int tid, int k0) {
  int r0 = tid >> 4;
  int c = (tid & 15) * 4;
#pragma unroll
  for (int it = 0; it < 8; ++it) {
    int r = r0 + it * 16;
    int rr = r < row_lim ? r : row_lim - 1;
    f32x4 v = *reinterpret_cast<const f32x4*>(src + (size_t)rr * ldA + k0 + c);
    *reinterpret_cast<u32x2*>(&As[swz(r, c)]) = pack4(v[0], v[1], v[2], v[3]);
  }
}

// Stage bf16 activation tile (k-contiguous) -> LDS, no conversion
DEVI void stage_a_bf16(short* As, const short* src, int ldA, int row_lim, int tid, int k0) {
#pragma unroll
  for (int it = 0; it < 4; ++it) {
    int slot = it * 256 + tid;
    int r = slot >> 3;
    int c = (slot & 7) * 8;
    int rr = r < row_lim ? r : row_lim - 1;
    i32x4 v = *reinterpret_cast<const i32x4*>(src + (size_t)rr * ldA + k0 + c);
    *reinterpret_cast<i32x4*>(&As[swz(r, c)]) = v;
  }
}

// Stage weight tile W[k0..k0+64)[n0..n0+128) (fp32, n-contiguous) transposed
// into LDS [n=128][k=64] bf16 swizzled. 4x4 micro-tile in-register transpose,
// write order rotated by lane to spread LDS banks (~4-way instead of 16-way).
DEVI void stage_b_f32t(short* Bs, const float* src, int ldB, int tid, int k0) {
  int n4 = tid & 31;
  int kq = tid >> 5;
  int lrot = (tid >> 2) & 3;
#pragma unroll
  for (int it = 0; it < 2; ++it) {
    int k4 = kq + it * 8;
    const float* p = src + (size_t)(k0 + k4 * 4) * ldB + n4 * 4;
    f32x4 v[4];
#pragma unroll
    for (int j = 0; j < 4; ++j) v[j] = *reinterpret_cast<const f32x4*>(p + (size_t)j * ldB);
#pragma unroll
    for (int ii = 0; ii < 4; ++ii) {
      int i = (ii + lrot) & 3;
      *reinterpret_cast<u32x2*>(&Bs[swz(n4 * 4 + i, k4 * 4)]) =
          pack4(v[0][i], v[1][i], v[2][i], v[3][i]);
    }
  }
}

__global__ __launch_bounds__(256, 2) void gate_up_kernel(
    const float* __restrict__ x, const float* __restrict__ wg,
    const float* __restrict__ wu, const int* __restrict__ gsz,
    short* __restrict__ act, int T) {
  const int e = blockIdx.z;
  int row_start = 0;
  for (int i = 0; i < e; ++i) row_start += gsz[i];
  const int rows = gsz[e];
  const int m0 = blockIdx.y * BM;
  if (m0 >= rows) return;
  const int n0 = blockIdx.x * BN;
  const int row_lim = rows - m0;

  __shared__ __align__(16) short As[BM * BK];
  __shared__ __align__(16) short Bgs[BN * BK];
  __shared__ __align__(16) short Bus[BN * BK];

  const int tid = threadIdx.x;
  const int l = tid & 63;
  const int wid = tid >> 6;
  const int wr = (wid >> 1) * 64;  // wave row base in 128x128 tile
  const int wc = (wid & 1) * 64;   // wave col base
  const int lr = l & 15;
  const int kb = (l >> 4) * 8;

  const float* xa = x + (size_t)(row_start + m0) * HID;
  const float* wga = wg + (size_t)e * HID * INTER + n0;
  const float* wua = wu + (size_t)e * HID * INTER + n0;

  f32x4 accg[4][4] = {};
  f32x4 accu[4][4] = {};

  for (int k0 = 0; k0 < HID; k0 += BK) {
    stage_a_f32(As, xa, HID, row_lim, tid, k0);
    stage_b_f32t(Bgs, wga, INTER, tid, k0);
    stage_b_f32t(Bus, wua, INTER, tid, k0);
    __syncthreads();
#pragma unroll
    for (int kk = 0; kk < BK; kk += 32) {
      bf16x8 a[4], b[4];
#pragma unroll
      for (int mi = 0; mi < 4; ++mi)
        a[mi] = *reinterpret_cast<const bf16x8*>(&As[swz(wr + mi * 16 + lr, kk + kb)]);
#pragma unroll
      for (int ni = 0; ni < 4; ++ni)
        b[ni] = *reinterpret_cast<const bf16x8*>(&Bgs[swz(wc + ni * 16 + lr, kk + kb)]);
#pragma unroll
      for (int mi = 0; mi < 4; ++mi)
#pragma unroll
        for (int ni = 0; ni < 4; ++ni)
          accg[mi][ni] = __builtin_amdgcn_mfma_f32_16x16x32_bf16(a[mi], b[ni], accg[mi][ni], 0, 0, 0);
#pragma unroll
      for (int ni = 0; ni < 4; ++ni)
        b[ni] = *reinterpret_cast<const bf16x8*>(&Bus[swz(wc + ni * 16 + lr, kk + kb)]);
#pragma unroll
      for (int mi = 0; mi < 4; ++mi)
#pragma unroll
        for (int ni = 0; ni < 4; ++ni)
          accu[mi][ni] = __builtin_amdgcn_mfma_f32_16x16x32_bf16(a[mi], b[ni], accu[mi][ni], 0, 0, 0);
    }
    __syncthreads();
  }

  // Epilogue: silu(gate) * up -> bf16 act
  short* actp = act + (size_t)(row_start + m0) * INTER + n0;
#pragma unroll
  for (int mi = 0; mi < 4; ++mi) {
#pragma unroll
    for (int r = 0; r < 4; ++r) {
      int rloc = wr + mi * 16 + (l >> 4) * 4 + r;
      if (rloc < row_lim) {
#pragma unroll
        for (int ni = 0; ni < 4; ++ni) {
          float g = accg[mi][ni][r];
          float u = accu[mi][ni][r];
          float s = g / (1.0f + expf(-g));
          actp[(size_t)rloc * INTER + wc + ni * 16 + lr] = f2bf(s * u);
        }
      }
    }
  }
}

__global__ __launch_bounds__(256, 2) void down_kernel(
    const short* __restrict__ act, const float* __restrict__ wd,
    const int* __restrict__ gsz, float* __restrict__ out, int T) {
  const int e = blockIdx.z;
  int row_start = 0;
  for (int i = 0; i < e; ++i) row_start += gsz[i];
  const int rows = gsz[e];
  const int m0 = blockIdx.y * BM;
  if (m0 >= rows) return;
  const int n0 = blockIdx.x * BN;
  const int row_lim = rows - m0;

  __shared__ __align__(16) short As[BM * BK];
  __shared__ __align__(16) short Bs[BN * BK];

  const int tid = threadIdx.x;
  const int l = tid & 63;
  const int wid = tid >> 6;
  const int wr = (wid >> 1) * 64;
  const int wc = (wid & 1) * 64;
  const int lr = l & 15;
  const int kb = (l >> 4) * 8;

  const short* aa = act + (size_t)(row_start + m0) * INTER;
  const float* wda = wd + (size_t)e * INTER * HID + n0;

  f32x4 acc[4][4] = {};

  for (int k0 = 0; k0 < INTER; k0 += BK) {
    stage_a_bf16(As, aa, INTER, row_lim, tid, k0);
    stage_b_f32t(Bs, wda, HID, tid, k0);
    __syncthreads();
#pragma unroll
    for (int kk = 0; kk < BK; kk += 32) {
      bf16x8 a[4], b[4];
#pragma unroll
      for (int mi = 0; mi < 4; ++mi)
        a[mi] = *reinterpret_cast<const bf16x8*>(&As[swz(wr + mi * 16 + lr, kk + kb)]);
#pragma unroll
      for (int ni = 0; ni < 4; ++ni)
        b[ni] = *reinterpret_cast<const bf16x8*>(&Bs[swz(wc + ni * 16 + lr, kk + kb)]);
#pragma unroll
      for (int mi = 0; mi < 4; ++mi)
#pragma unroll
        for (int ni = 0; ni < 4; ++ni)
          acc[mi][ni] = __builtin_amdgcn_mfma_f32_16x16x32_bf16(a[mi], b[ni], acc[mi][ni], 0, 0, 0);
    }
    __syncthreads();
  }

  float* outp = out + (size_t)(row_start + m0) * HID + n0;
#pragma unroll
  for (int mi = 0; mi < 4; ++mi) {
#pragma unroll
    for (int r = 0; r < 4; ++r) {
      int rloc = wr + mi * 16 + (l >> 4) * 4 + r;
      if (rloc < row_lim) {
#pragma unroll
        for (int ni = 0; ni < 4; ++ni)
          outp[(size_t)rloc * HID + wc + ni * 16 + lr] = acc[mi][ni][r];
      }
    }
  }
}

extern "C" void kernel_launch(void* const* d_in, const int* in_sizes, int n_in,
                              void* d_out, int out_size, void* d_ws, size_t ws_size,
                              hipStream_t stream) {
  const float* x = (const float*)d_in[0];
  const float* wg = (const float*)d_in[1];
  const float* wu = (const float*)d_in[2];
  const float* wd = (const float*)d_in[3];
  const int* gsz = (const int*)d_in[4];
  float* out = (float*)d_out;
  short* act = (short*)d_ws;  // bf16 [T][INTER], 16 MB

  const int T = in_sizes[0] / HID;
  const int mtiles = (T + BM - 1) / BM;  // worst case: one expert owns all tokens

  dim3 blk(256, 1, 1);
  dim3 g1(INTER / BN, mtiles, NE);
  gate_up_kernel<<<g1, blk, 0, stream>>>(x, wg, wu, gsz, act, T);
  dim3 g2(HID / BN, mtiles, NE);
  down_kernel<<<g2, blk, 0, stream>>>(act, wd, gsz, out, T);
}

// Round 2
// 336.747 us; speedup vs baseline: 1.1858x; 1.1858x over previous
//
#include <hip/hip_runtime.h>
#include <hip/hip_bf16.h>

#define DEVI static __device__ __forceinline__

typedef __attribute__((ext_vector_type(8))) short bf16x8;
typedef __attribute__((ext_vector_type(4))) float f32x4;
typedef __attribute__((ext_vector_type(4))) int i32x4;
typedef __attribute__((ext_vector_type(2))) unsigned u32x2;

constexpr int NE = 8;
constexpr int HID = 1024;
constexpr int INTER = 2048;
constexpr int BM = 64, BN = 64, BK = 64;

// LDS tiles are [row][BK=64] bf16, XOR-swizzled (element ^ ((r&7)<<3)) to
// break the 128B-row same-bank column on ds_read_b128 (G4 / T2).
DEVI int swz(int r, int c) { return (r * BK + c) ^ ((r & 7) << 3); }

DEVI short f2bf(float f) {
  union { float f; unsigned u; } v;
  v.f = f;
  unsigned r = v.u + 0x7FFFu + ((v.u >> 16) & 1u);  // round-to-nearest-even
  return (short)(r >> 16);
}

DEVI u32x2 pack4(float a, float b, float c, float d) {
  u32x2 o;
  o[0] = (unsigned)(unsigned short)f2bf(a) | ((unsigned)(unsigned short)f2bf(b) << 16);
  o[1] = (unsigned)(unsigned short)f2bf(c) | ((unsigned)(unsigned short)f2bf(d) << 16);
  return o;
}

// ---------------------------------------------------------------------------
// gate_up: act[t][n] = silu(x@Wg) * (x@Wu), bf16 out. Tile 64x64, 4 waves
// (2x2), wave tile 32x32, dual accumulators. 2-phase pipeline: load regs for
// tile t+1 -> MFMA tile t -> convert+ds_write t+1 -> barrier.
// ---------------------------------------------------------------------------
__global__ __launch_bounds__(256, 2) void gate_up_kernel(
    const float* __restrict__ x, const float* __restrict__ wg,
    const float* __restrict__ wu, const int* __restrict__ gsz,
    short* __restrict__ act) {
  const int e = blockIdx.z;
  int row_start = 0;
  for (int i = 0; i < e; ++i) row_start += gsz[i];
  const int rows = gsz[e];
  const int m0 = blockIdx.y * BM;
  if (m0 >= rows) return;
  const int n0 = blockIdx.x * BN;
  const int row_lim = rows - m0;

  __shared__ __align__(16) short As[2][BM * BK];
  __shared__ __align__(16) short Bgs[2][BN * BK];
  __shared__ __align__(16) short Bus[2][BN * BK];

  const int tid = threadIdx.x;
  const int l = tid & 63;
  const int wid = tid >> 6;
  const int wr = (wid >> 1) * 32;
  const int wc = (wid & 1) * 32;
  const int lr = l & 15;
  const int kb = (l >> 4) * 8;

  const float* xa = x + (size_t)(row_start + m0) * HID;
  const float* wga = wg + (size_t)e * HID * INTER + n0;
  const float* wua = wu + (size_t)e * HID * INTER + n0;

  const int ar = tid >> 4;        // A row base 0..15
  const int ac = (tid & 15) * 4;  // A col 0..60
  const int bn4 = tid & 15;       // B n-quad
  const int bkq = tid >> 4;       // B k-quad 0..15
  const int lrot = tid & 3;

  f32x4 ra[4], rbg[4], rbu[4];

  auto load_tile = [&](int k0) {
#pragma unroll
    for (int it = 0; it < 4; ++it) {
      int r = ar + it * 16;
      int rr = r < row_lim ? r : row_lim - 1;
      ra[it] = *reinterpret_cast<const f32x4*>(xa + (size_t)rr * HID + k0 + ac);
    }
    const float* pg = wga + (size_t)(k0 + bkq * 4) * INTER + bn4 * 4;
    const float* pu = wua + (size_t)(k0 + bkq * 4) * INTER + bn4 * 4;
#pragma unroll
    for (int j = 0; j < 4; ++j) rbg[j] = *reinterpret_cast<const f32x4*>(pg + (size_t)j * INTER);
#pragma unroll
    for (int j = 0; j < 4; ++j) rbu[j] = *reinterpret_cast<const f32x4*>(pu + (size_t)j * INTER);
  };

  auto write_tile = [&](int buf) {
    short* As_ = As[buf];
    short* Bg_ = Bgs[buf];
    short* Bu_ = Bus[buf];
#pragma unroll
    for (int it = 0; it < 4; ++it) {
      int r = ar + it * 16;
      *reinterpret_cast<u32x2*>(&As_[swz(r, ac)]) =
          pack4(ra[it][0], ra[it][1], ra[it][2], ra[it][3]);
    }
#pragma unroll
    for (int ii = 0; ii < 4; ++ii) {
      int i = (ii + lrot) & 3;  // lane-rotated write order: spread banks
      *reinterpret_cast<u32x2*>(&Bg_[swz(bn4 * 4 + i, bkq * 4)]) =
          pack4(rbg[0][i], rbg[1][i], rbg[2][i], rbg[3][i]);
    }
#pragma unroll
    for (int ii = 0; ii < 4; ++ii) {
      int i = (ii + lrot) & 3;
      *reinterpret_cast<u32x2*>(&Bu_[swz(bn4 * 4 + i, bkq * 4)]) =
          pack4(rbu[0][i], rbu[1][i], rbu[2][i], rbu[3][i]);
    }
  };

  f32x4 accg[2][2] = {};
  f32x4 accu[2][2] = {};

  constexpr int NT = HID / BK;  // 16
  load_tile(0);
  write_tile(0);
  __syncthreads();

  for (int kt = 0; kt < NT; ++kt) {
    if (kt + 1 < NT) load_tile((kt + 1) * BK);  // issue next-tile loads early
    const short* As_ = As[kt & 1];
    const short* Bg_ = Bgs[kt & 1];
    const short* Bu_ = Bus[kt & 1];
#pragma unroll
    for (int kk = 0; kk < BK; kk += 32) {
      bf16x8 a[2], bg[2], bu[2];
#pragma unroll
      for (int mi = 0; mi < 2; ++mi)
        a[mi] = *reinterpret_cast<const bf16x8*>(&As_[swz(wr + mi * 16 + lr, kk + kb)]);
#pragma unroll
      for (int ni = 0; ni < 2; ++ni) {
        bg[ni] = *reinterpret_cast<const bf16x8*>(&Bg_[swz(wc + ni * 16 + lr, kk + kb)]);
        bu[ni] = *reinterpret_cast<const bf16x8*>(&Bu_[swz(wc + ni * 16 + lr, kk + kb)]);
      }
#pragma unroll
      for (int mi = 0; mi < 2; ++mi)
#pragma unroll
        for (int ni = 0; ni < 2; ++ni) {
          accg[mi][ni] = __builtin_amdgcn_mfma_f32_16x16x32_bf16(a[mi], bg[ni], accg[mi][ni], 0, 0, 0);
          accu[mi][ni] = __builtin_amdgcn_mfma_f32_16x16x32_bf16(a[mi], bu[ni], accu[mi][ni], 0, 0, 0);
        }
    }
    if (kt + 1 < NT) write_tile((kt + 1) & 1);  // vmcnt wait lands here
    __syncthreads();
  }

  short* actp = act + (size_t)(row_start + m0) * INTER + n0;
#pragma unroll
  for (int mi = 0; mi < 2; ++mi) {
#pragma unroll
    for (int r = 0; r < 4; ++r) {
      int rloc = wr + mi * 16 + (l >> 4) * 4 + r;
      if (rloc < row_lim) {
#pragma unroll
        for (int ni = 0; ni < 2; ++ni) {
          float g = accg[mi][ni][r];
          float u = accu[mi][ni][r];
          float s = g / (1.0f + __expf(-g));
          actp[(size_t)rloc * INTER + wc + ni * 16 + lr] = f2bf(s * u);
        }
      }
    }
  }
}

// ---------------------------------------------------------------------------
// down: out[t][h] = act @ Wd. Same structure; A is bf16 (no convert).
// ---------------------------------------------------------------------------
__global__ __launch_bounds__(256, 2) void down_kernel(
    const short* __restrict__ act, const float* __restrict__ wd,
    const int* __restrict__ gsz, float* __restrict__ out) {
  const int e = blockIdx.z;
  int row_start = 0;
  for (int i = 0; i < e; ++i) row_start += gsz[i];
  const int rows = gsz[e];
  const int m0 = blockIdx.y * BM;
  if (m0 >= rows) return;
  const int n0 = blockIdx.x * BN;
  const int row_lim = rows - m0;

  __shared__ __align__(16) short As[2][BM * BK];
  __shared__ __align__(16) short Bs[2][BN * BK];

  const int tid = threadIdx.x;
  const int l = tid & 63;
  const int wid = tid >> 6;
  const int wr = (wid >> 1) * 32;
  const int wc = (wid & 1) * 32;
  const int lr = l & 15;
  const int kb = (l >> 4) * 8;

  const short* aa = act + (size_t)(row_start + m0) * INTER;
  const float* wda = wd + (size_t)e * INTER * HID + n0;

  const int ar = (tid >> 3);        // with it*32: rows 0..63
  const int ac = (tid & 7) * 8;     // 0..56
  const int bn4 = tid & 15;
  const int bkq = tid >> 4;
  const int lrot = tid & 3;

  i32x4 raa[2];
  f32x4 rb[4];

  auto load_tile = [&](int k0) {
#pragma unroll
    for (int it = 0; it < 2; ++it) {
      int r = ar + it * 32;
      int rr = r < row_lim ? r : row_lim - 1;
      raa[it] = *reinterpret_cast<const i32x4*>(aa + (size_t)rr * INTER + k0 + ac);
    }
    const float* pb = wda + (size_t)(k0 + bkq * 4) * HID + bn4 * 4;
#pragma unroll
    for (int j = 0; j < 4; ++j) rb[j] = *reinterpret_cast<const f32x4*>(pb + (size_t)j * HID);
  };

  auto write_tile = [&](int buf) {
    short* As_ = As[buf];
    short* Bs_ = Bs[buf];
#pragma unroll
    for (int it = 0; it < 2; ++it) {
      int r = ar + it * 32;
      *reinterpret_cast<i32x4*>(&As_[swz(r, ac)]) = raa[it];
    }
#pragma unroll
    for (int ii = 0; ii < 4; ++ii) {
      int i = (ii + lrot) & 3;
      *reinterpret_cast<u32x2*>(&Bs_[swz(bn4 * 4 + i, bkq * 4)]) =
          pack4(rb[0][i], rb[1][i], rb[2][i], rb[3][i]);
    }
  };

  f32x4 acc[2][2] = {};

  constexpr int NT = INTER / BK;  // 32
  load_tile(0);
  write_tile(0);
  __syncthreads();

  for (int kt = 0; kt < NT; ++kt) {
    if (kt + 1 < NT) load_tile((kt + 1) * BK);
    const short* As_ = As[kt & 1];
    const short* Bs_ = Bs[kt & 1];
#pragma unroll
    for (int kk = 0; kk < BK; kk += 32) {
      bf16x8 a[2], b[2];
#pragma unroll
      for (int mi = 0; mi < 2; ++mi)
        a[mi] = *reinterpret_cast<const bf16x8*>(&As_[swz(wr + mi * 16 + lr, kk + kb)]);
#pragma unroll
      for (int ni = 0; ni < 2; ++ni)
        b[ni] = *reinterpret_cast<const bf16x8*>(&Bs_[swz(wc + ni * 16 + lr, kk + kb)]);
#pragma unroll
      for (int mi = 0; mi < 2; ++mi)
#pragma unroll
        for (int ni = 0; ni < 2; ++ni)
          acc[mi][ni] = __builtin_amdgcn_mfma_f32_16x16x32_bf16(a[mi], b[ni], acc[mi][ni], 0, 0, 0);
    }
    if (kt + 1 < NT) write_tile((kt + 1) & 1);
    __syncthreads();
  }

  float* outp = out + (size_t)(row_start + m0) * HID + n0;
#pragma unroll
  for (int mi = 0; mi < 2; ++mi) {
#pragma unroll
    for (int r = 0; r < 4; ++r) {
      int rloc = wr + mi * 16 + (l >> 4) * 4 + r;
      if (rloc < row_lim) {
#pragma unroll
        for (int ni = 0; ni < 2; ++ni)
          outp[(size_t)rloc * HID + wc + ni * 16 + lr] = acc[mi][ni][r];
      }
    }
  }
}

extern "C" void kernel_launch(void* const* d_in, const int* in_sizes, int n_in,
                              void* d_out, int out_size, void* d_ws, size_t ws_size,
                              hipStream_t stream) {
  const float* x = (const float*)d_in[0];
  const float* wg = (const float*)d_in[1];
  const float* wu = (const float*)d_in[2];
  const float* wd = (const float*)d_in[3];
  const int* gsz = (const int*)d_in[4];
  float* out = (float*)d_out;
  short* act = (short*)d_ws;  // bf16 [T][INTER], 16 MB

  const int T = in_sizes[0] / HID;
  const int mtiles = (T + BM - 1) / BM;  // worst case: one expert owns all tokens

  dim3 blk(256, 1, 1);
  gate_up_kernel<<<dim3(INTER / BN, mtiles, NE), blk, 0, stream>>>(x, wg, wu, gsz, act);
  down_kernel<<<dim3(HID / BN, mtiles, NE), blk, 0, stream>>>(act, wd, gsz, out);
}

// Round 3
// 322.048 us; speedup vs baseline: 1.2399x; 1.0456x over previous
//
#include <hip/hip_runtime.h>
#include <hip/hip_bf16.h>

#define DEVI static __device__ __forceinline__

typedef __attribute__((ext_vector_type(8))) short bf16x8;
typedef __attribute__((ext_vector_type(4))) float f32x4;
typedef __attribute__((ext_vector_type(4))) int i32x4;
typedef __attribute__((ext_vector_type(2))) unsigned u32x2;

constexpr int NE = 8;
constexpr int HID = 1024;
constexpr int INTER = 2048;
constexpr int BM = 64, BN = 64, BK = 64;

// LDS tiles [row][64] bf16, XOR swizzle on the 8-elem granule (T2 / G4).
DEVI int swz(int r, int c) { return (r * BK + c) ^ ((r & 7) << 3); }

DEVI short f2bf(float f) {
  union { float f; unsigned u; } v;
  v.f = f;
  unsigned r = v.u + 0x7FFFu + ((v.u >> 16) & 1u);  // RNE
  return (short)(r >> 16);
}

DEVI u32x2 pack4(float a, float b, float c, float d) {
  u32x2 o;
  o[0] = (unsigned)(unsigned short)f2bf(a) | ((unsigned)(unsigned short)f2bf(b) << 16);
  o[1] = (unsigned)(unsigned short)f2bf(c) | ((unsigned)(unsigned short)f2bf(d) << 16);
  return o;
}

DEVI void gload16(const void* g, void* l) {
  __builtin_amdgcn_global_load_lds((const __attribute__((address_space(1))) void*)g,
                                   (__attribute__((address_space(3))) void*)l, 16, 0, 0);
}

// ===========================================================================
// Path A pre-passes
// ===========================================================================

// x f32 -> bf16, elementwise, 8 elems/thread
__global__ __launch_bounds__(256) void convert_x_kernel(const float* __restrict__ in,
                                                        short* __restrict__ out, int n) {
  int idx = (blockIdx.x * 256 + threadIdx.x) * 8;
  if (idx >= n) return;
  f32x4 a = *reinterpret_cast<const f32x4*>(in + idx);
  f32x4 b = *reinterpret_cast<const f32x4*>(in + idx + 4);
  i32x4 o;
  u32x2 p0 = pack4(a[0], a[1], a[2], a[3]);
  u32x2 p1 = pack4(b[0], b[1], b[2], b[3]);
  o[0] = p0[0]; o[1] = p0[1]; o[2] = p1[0]; o[3] = p1[1];
  *reinterpret_cast<i32x4*>(out + idx) = o;
}

// W[e][K][N] f32 -> Wt[e][N][K] bf16, 64x64 tiles via LDS
__global__ __launch_bounds__(256) void transpose_convert_kernel(
    const float* __restrict__ src, short* __restrict__ dst, int K, int N) {
  const int e = blockIdx.z;
  const int N0 = blockIdx.x * 64;
  const int K0 = blockIdx.y * 64;
  __shared__ __align__(16) short L[64 * 72];  // stride 72 shorts = 144B (16B aligned)

  const int t = threadIdx.x;
  const float* s = src + (size_t)e * K * N;
  short* d = dst + (size_t)e * N * K;

  {
    int n4 = t & 15;
    int kq = t >> 4;
    const float* p = s + (size_t)(K0 + kq * 4) * N + N0 + n4 * 4;
    f32x4 v[4];
#pragma unroll
    for (int j = 0; j < 4; ++j) v[j] = *reinterpret_cast<const f32x4*>(p + (size_t)j * N);
    int lrot = t & 3;
#pragma unroll
    for (int ii = 0; ii < 4; ++ii) {
      int i = (ii + lrot) & 3;
      *reinterpret_cast<u32x2*>(&L[(n4 * 4 + i) * 72 + kq * 4]) =
          pack4(v[0][i], v[1][i], v[2][i], v[3][i]);
    }
  }
  __syncthreads();
#pragma unroll
  for (int it = 0; it < 2; ++it) {
    int n = (t >> 3) + it * 32;
    int kg = t & 7;
    i32x4 v = *reinterpret_cast<const i32x4*>(&L[n * 72 + kg * 8]);
    *reinterpret_cast<i32x4*>(d + (size_t)(N0 + n) * K + K0 + kg * 8) = v;
  }
}

// ===========================================================================
// Path A GEMMs: bf16 operands, global_load_lds staging, 2-phase dbuf
// ===========================================================================
__global__ __launch_bounds__(256, 2) void gate_up_bf_kernel(
    const short* __restrict__ x, const short* __restrict__ wgt,
    const short* __restrict__ wut, const int* __restrict__ gsz,
    short* __restrict__ act) {
  const int e = blockIdx.z;
  int row_start = 0;
  for (int i = 0; i < e; ++i) row_start += gsz[i];
  const int rows = gsz[e];
  const int m0 = blockIdx.y * BM;
  if (m0 >= rows) return;
  const int n0 = blockIdx.x * BN;
  const int row_lim = rows - m0;

  __shared__ __align__(16) short As[2][BM * BK];
  __shared__ __align__(16) short Bgs[2][BN * BK];
  __shared__ __align__(16) short Bus[2][BN * BK];

  const int tid = threadIdx.x;
  const int l = tid & 63;
  const int wid = tid >> 6;
  const int wr = (wid >> 1) * 32;
  const int wc = (wid & 1) * 32;
  const int lr = l & 15;
  const int kb = (l >> 4) * 8;

  const short* xa = x + (size_t)(row_start + m0) * HID;
  const short* wga = wgt + (size_t)e * INTER * HID + (size_t)n0 * HID;  // [n][k]
  const short* wua = wut + (size_t)e * INTER * HID + (size_t)n0 * HID;

  auto stage = [&](int buf, int k0) {
    short* As_ = As[buf];
    short* Bg_ = Bgs[buf];
    short* Bu_ = Bus[buf];
#pragma unroll
    for (int s = 0; s < 2; ++s) {
      int r0 = wid * 16 + s * 8;
      int r = r0 + (l >> 3);
      int gg = (l & 7) ^ (r & 7);  // pre-swizzled source granule (rule 21)
      int rr = r < row_lim ? r : row_lim - 1;
      gload16(xa + (size_t)rr * HID + k0 + gg * 8, &As_[r0 * 64]);
      gload16(wga + (size_t)r * HID + k0 + gg * 8, &Bg_[r0 * 64]);
      gload16(wua + (size_t)r * HID + k0 + gg * 8, &Bu_[r0 * 64]);
    }
  };

  f32x4 accg[2][2] = {};
  f32x4 accu[2][2] = {};

  constexpr int NT = HID / BK;  // 16
  stage(0, 0);
  __syncthreads();

  for (int kt = 0; kt < NT; ++kt) {
    if (kt + 1 < NT) stage((kt + 1) & 1, (kt + 1) * BK);  // async into other buf
    const short* As_ = As[kt & 1];
    const short* Bg_ = Bgs[kt & 1];
    const short* Bu_ = Bus[kt & 1];
#pragma unroll
    for (int kk = 0; kk < BK; kk += 32) {
      bf16x8 a[2], bg[2], bu[2];
#pragma unroll
      for (int mi = 0; mi < 2; ++mi)
        a[mi] = *reinterpret_cast<const bf16x8*>(&As_[swz(wr + mi * 16 + lr, kk + kb)]);
#pragma unroll
      for (int ni = 0; ni < 2; ++ni) {
        bg[ni] = *reinterpret_cast<const bf16x8*>(&Bg_[swz(wc + ni * 16 + lr, kk + kb)]);
        bu[ni] = *reinterpret_cast<const bf16x8*>(&Bu_[swz(wc + ni * 16 + lr, kk + kb)]);
      }
#pragma unroll
      for (int mi = 0; mi < 2; ++mi)
#pragma unroll
        for (int ni = 0; ni < 2; ++ni) {
          accg[mi][ni] = __builtin_amdgcn_mfma_f32_16x16x32_bf16(a[mi], bg[ni], accg[mi][ni], 0, 0, 0);
          accu[mi][ni] = __builtin_amdgcn_mfma_f32_16x16x32_bf16(a[mi], bu[ni], accu[mi][ni], 0, 0, 0);
        }
    }
    __syncthreads();  // drains vmcnt(0)+lgkmcnt(0): next buf staged, reads done
  }

  short* actp = act + (size_t)(row_start + m0) * INTER + n0;
#pragma unroll
  for (int mi = 0; mi < 2; ++mi) {
#pragma unroll
    for (int r = 0; r < 4; ++r) {
      int rloc = wr + mi * 16 + (l >> 4) * 4 + r;
      if (rloc < row_lim) {
#pragma unroll
        for (int ni = 0; ni < 2; ++ni) {
          float g = accg[mi][ni][r];
          float u = accu[mi][ni][r];
          float s = g / (1.0f + __expf(-g));
          actp[(size_t)rloc * INTER + wc + ni * 16 + lr] = f2bf(s * u);
        }
      }
    }
  }
}

__global__ __launch_bounds__(256, 2) void down_bf_kernel(
    const short* __restrict__ act, const short* __restrict__ wdt,
    const int* __restrict__ gsz, float* __restrict__ out) {
  const int e = blockIdx.z;
  int row_start = 0;
  for (int i = 0; i < e; ++i) row_start += gsz[i];
  const int rows = gsz[e];
  const int m0 = blockIdx.y * BM;
  if (m0 >= rows) return;
  const int n0 = blockIdx.x * BN;
  const int row_lim = rows - m0;

  __shared__ __align__(16) short As[2][BM * BK];
  __shared__ __align__(16) short Bs[2][BN * BK];

  const int tid = threadIdx.x;
  const int l = tid & 63;
  const int wid = tid >> 6;
  const int wr = (wid >> 1) * 32;
  const int wc = (wid & 1) * 32;
  const int lr = l & 15;
  const int kb = (l >> 4) * 8;

  const short* aa = act + (size_t)(row_start + m0) * INTER;
  const short* wda = wdt + (size_t)e * HID * INTER + (size_t)n0 * INTER;  // [h][i]

  auto stage = [&](int buf, int k0) {
    short* As_ = As[buf];
    short* Bs_ = Bs[buf];
#pragma unroll
    for (int s = 0; s < 2; ++s) {
      int r0 = wid * 16 + s * 8;
      int r = r0 + (l >> 3);
      int gg = (l & 7) ^ (r & 7);
      int rr = r < row_lim ? r : row_lim - 1;
      gload16(aa + (size_t)rr * INTER + k0 + gg * 8, &As_[r0 * 64]);
      gload16(wda + (size_t)r * INTER + k0 + gg * 8, &Bs_[r0 * 64]);
    }
  };

  f32x4 acc[2][2] = {};

  constexpr int NT = INTER / BK;  // 32
  stage(0, 0);
  __syncthreads();

  for (int kt = 0; kt < NT; ++kt) {
    if (kt + 1 < NT) stage((kt + 1) & 1, (kt + 1) * BK);
    const short* As_ = As[kt & 1];
    const short* Bs_ = Bs[kt & 1];
#pragma unroll
    for (int kk = 0; kk < BK; kk += 32) {
      bf16x8 a[2], b[2];
#pragma unroll
      for (int mi = 0; mi < 2; ++mi)
        a[mi] = *reinterpret_cast<const bf16x8*>(&As_[swz(wr + mi * 16 + lr, kk + kb)]);
#pragma unroll
      for (int ni = 0; ni < 2; ++ni)
        b[ni] = *reinterpret_cast<const bf16x8*>(&Bs_[swz(wc + ni * 16 + lr, kk + kb)]);
#pragma unroll
      for (int mi = 0; mi < 2; ++mi)
#pragma unroll
        for (int ni = 0; ni < 2; ++ni)
          acc[mi][ni] = __builtin_amdgcn_mfma_f32_16x16x32_bf16(a[mi], b[ni], acc[mi][ni], 0, 0, 0);
    }
    __syncthreads();
  }

  float* outp = out + (size_t)(row_start + m0) * HID + n0;
#pragma unroll
  for (int mi = 0; mi < 2; ++mi) {
#pragma unroll
    for (int r = 0; r < 4; ++r) {
      int rloc = wr + mi * 16 + (l >> 4) * 4 + r;
      if (rloc < row_lim) {
#pragma unroll
        for (int ni = 0; ni < 2; ++ni)
          outp[(size_t)rloc * HID + wc + ni * 16 + lr] = acc[mi][ni][r];
      }
    }
  }
}

// ===========================================================================
// Path B (fallback if ws too small): round-2 kernels, fp32 in-flight convert
// ===========================================================================
__global__ __launch_bounds__(256, 2) void gate_up_kernel(
    const float* __restrict__ x, const float* __restrict__ wg,
    const float* __restrict__ wu, const int* __restrict__ gsz,
    short* __restrict__ act) {
  const int e = blockIdx.z;
  int row_start = 0;
  for (int i = 0; i < e; ++i) row_start += gsz[i];
  const int rows = gsz[e];
  const int m0 = blockIdx.y * BM;
  if (m0 >= rows) return;
  const int n0 = blockIdx.x * BN;
  const int row_lim = rows - m0;

  __shared__ __align__(16) short As[2][BM * BK];
  __shared__ __align__(16) short Bgs[2][BN * BK];
  __shared__ __align__(16) short Bus[2][BN * BK];

  const int tid = threadIdx.x;
  const int l = tid & 63;
  const int wid = tid >> 6;
  const int wr = (wid >> 1) * 32;
  const int wc = (wid & 1) * 32;
  const int lr = l & 15;
  const int kb = (l >> 4) * 8;

  const float* xa = x + (size_t)(row_start + m0) * HID;
  const float* wga = wg + (size_t)e * HID * INTER + n0;
  const float* wua = wu + (size_t)e * HID * INTER + n0;

  const int ar = tid >> 4;
  const int ac = (tid & 15) * 4;
  const int bn4 = tid & 15;
  const int bkq = tid >> 4;
  const int lrot = tid & 3;

  f32x4 ra[4], rbg[4], rbu[4];

  auto load_tile = [&](int k0) {
#pragma unroll
    for (int it = 0; it < 4; ++it) {
      int r = ar + it * 16;
      int rr = r < row_lim ? r : row_lim - 1;
      ra[it] = *reinterpret_cast<const f32x4*>(xa + (size_t)rr * HID + k0 + ac);
    }
    const float* pg = wga + (size_t)(k0 + bkq * 4) * INTER + bn4 * 4;
    const float* pu = wua + (size_t)(k0 + bkq * 4) * INTER + bn4 * 4;
#pragma unroll
    for (int j = 0; j < 4; ++j) rbg[j] = *reinterpret_cast<const f32x4*>(pg + (size_t)j * INTER);
#pragma unroll
    for (int j = 0; j < 4; ++j) rbu[j] = *reinterpret_cast<const f32x4*>(pu + (size_t)j * INTER);
  };

  auto write_tile = [&](int buf) {
    short* As_ = As[buf];
    short* Bg_ = Bgs[buf];
    short* Bu_ = Bus[buf];
#pragma unroll
    for (int it = 0; it < 4; ++it) {
      int r = ar + it * 16;
      *reinterpret_cast<u32x2*>(&As_[swz(r, ac)]) =
          pack4(ra[it][0], ra[it][1], ra[it][2], ra[it][3]);
    }
#pragma unroll
    for (int ii = 0; ii < 4; ++ii) {
      int i = (ii + lrot) & 3;
      *reinterpret_cast<u32x2*>(&Bg_[swz(bn4 * 4 + i, bkq * 4)]) =
          pack4(rbg[0][i], rbg[1][i], rbg[2][i], rbg[3][i]);
    }
#pragma unroll
    for (int ii = 0; ii < 4; ++ii) {
      int i = (ii + lrot) & 3;
      *reinterpret_cast<u32x2*>(&Bu_[swz(bn4 * 4 + i, bkq * 4)]) =
          pack4(rbu[0][i], rbu[1][i], rbu[2][i], rbu[3][i]);
    }
  };

  f32x4 accg[2][2] = {};
  f32x4 accu[2][2] = {};

  constexpr int NT = HID / BK;
  load_tile(0);
  write_tile(0);
  __syncthreads();

  for (int kt = 0; kt < NT; ++kt) {
    if (kt + 1 < NT) load_tile((kt + 1) * BK);
    const short* As_ = As[kt & 1];
    const short* Bg_ = Bgs[kt & 1];
    const short* Bu_ = Bus[kt & 1];
#pragma unroll
    for (int kk = 0; kk < BK; kk += 32) {
      bf16x8 a[2], bg[2], bu[2];
#pragma unroll
      for (int mi = 0; mi < 2; ++mi)
        a[mi] = *reinterpret_cast<const bf16x8*>(&As_[swz(wr + mi * 16 + lr, kk + kb)]);
#pragma unroll
      for (int ni = 0; ni < 2; ++ni) {
        bg[ni] = *reinterpret_cast<const bf16x8*>(&Bg_[swz(wc + ni * 16 + lr, kk + kb)]);
        bu[ni] = *reinterpret_cast<const bf16x8*>(&Bu_[swz(wc + ni * 16 + lr, kk + kb)]);
      }
#pragma unroll
      for (int mi = 0; mi < 2; ++mi)
#pragma unroll
        for (int ni = 0; ni < 2; ++ni) {
          accg[mi][ni] = __builtin_amdgcn_mfma_f32_16x16x32_bf16(a[mi], bg[ni], accg[mi][ni], 0, 0, 0);
          accu[mi][ni] = __builtin_amdgcn_mfma_f32_16x16x32_bf16(a[mi], bu[ni], accu[mi][ni], 0, 0, 0);
        }
    }
    if (kt + 1 < NT) write_tile((kt + 1) & 1);
    __syncthreads();
  }

  short* actp = act + (size_t)(row_start + m0) * INTER + n0;
#pragma unroll
  for (int mi = 0; mi < 2; ++mi) {
#pragma unroll
    for (int r = 0; r < 4; ++r) {
      int rloc = wr + mi * 16 + (l >> 4) * 4 + r;
      if (rloc < row_lim) {
#pragma unroll
        for (int ni = 0; ni < 2; ++ni) {
          float g = accg[mi][ni][r];
          float u = accu[mi][ni][r];
          float s = g / (1.0f + __expf(-g));
          actp[(size_t)rloc * INTER + wc + ni * 16 + lr] = f2bf(s * u);
        }
      }
    }
  }
}

__global__ __launch_bounds__(256, 2) void down_kernel(
    const short* __restrict__ act, const float* __restrict__ wd,
    const int* __restrict__ gsz, float* __restrict__ out) {
  const int e = blockIdx.z;
  int row_start = 0;
  for (int i = 0; i < e; ++i) row_start += gsz[i];
  const int rows = gsz[e];
  const int m0 = blockIdx.y * BM;
  if (m0 >= rows) return;
  const int n0 = blockIdx.x * BN;
  const int row_lim = rows - m0;

  __shared__ __align__(16) short As[2][BM * BK];
  __shared__ __align__(16) short Bs[2][BN * BK];

  const int tid = threadIdx.x;
  const int l = tid & 63;
  const int wid = tid >> 6;
  const int wr = (wid >> 1) * 32;
  const int wc = (wid & 1) * 32;
  const int lr = l & 15;
  const int kb = (l >> 4) * 8;

  const short* aa = act + (size_t)(row_start + m0) * INTER;
  const float* wda = wd + (size_t)e * INTER * HID + n0;

  const int ar = (tid >> 3);
  const int ac = (tid & 7) * 8;
  const int bn4 = tid & 15;
  const int bkq = tid >> 4;
  const int lrot = tid & 3;

  i32x4 raa[2];
  f32x4 rb[4];

  auto load_tile = [&](int k0) {
#pragma unroll
    for (int it = 0; it < 2; ++it) {
      int r = ar + it * 32;
      int rr = r < row_lim ? r : row_lim - 1;
      raa[it] = *reinterpret_cast<const i32x4*>(aa + (size_t)rr * INTER + k0 + ac);
    }
    const float* pb = wda + (size_t)(k0 + bkq * 4) * HID + bn4 * 4;
#pragma unroll
    for (int j = 0; j < 4; ++j) rb[j] = *reinterpret_cast<const f32x4*>(pb + (size_t)j * HID);
  };

  auto write_tile = [&](int buf) {
    short* As_ = As[buf];
    short* Bs_ = Bs[buf];
#pragma unroll
    for (int it = 0; it < 2; ++it) {
      int r = ar + it * 32;
      *reinterpret_cast<i32x4*>(&As_[swz(r, ac)]) = raa[it];
    }
#pragma unroll
    for (int ii = 0; ii < 4; ++ii) {
      int i = (ii + lrot) & 3;
      *reinterpret_cast<u32x2*>(&Bs_[swz(bn4 * 4 + i, bkq * 4)]) =
          pack4(rb[0][i], rb[1][i], rb[2][i], rb[3][i]);
    }
  };

  f32x4 acc[2][2] = {};

  constexpr int NT = INTER / BK;
  load_tile(0);
  write_tile(0);
  __syncthreads();

  for (int kt = 0; kt < NT; ++kt) {
    if (kt + 1 < NT) load_tile((kt + 1) * BK);
    const short* As_ = As[kt & 1];
    const short* Bs_ = Bs[kt & 1];
#pragma unroll
    for (int kk = 0; kk < BK; kk += 32) {
      bf16x8 a[2], b[2];
#pragma unroll
      for (int mi = 0; mi < 2; ++mi)
        a[mi] = *reinterpret_cast<const bf16x8*>(&As_[swz(wr + mi * 16 + lr, kk + kb)]);
#pragma unroll
      for (int ni = 0; ni < 2; ++ni)
        b[ni] = *reinterpret_cast<const bf16x8*>(&Bs_[swz(wc + ni * 16 + lr, kk + kb)]);
#pragma unroll
      for (int mi = 0; mi < 2; ++mi)
#pragma unroll
        for (int ni = 0; ni < 2; ++ni)
          acc[mi][ni] = __builtin_amdgcn_mfma_f32_16x16x32_bf16(a[mi], b[ni], acc[mi][ni], 0, 0, 0);
    }
    if (kt + 1 < NT) write_tile((kt + 1) & 1);
    __syncthreads();
  }

  float* outp = out + (size_t)(row_start + m0) * HID + n0;
#pragma unroll
  for (int mi = 0; mi < 2; ++mi) {
#pragma unroll
    for (int r = 0; r < 4; ++r) {
      int rloc = wr + mi * 16 + (l >> 4) * 4 + r;
      if (rloc < row_lim) {
#pragma unroll
        for (int ni = 0; ni < 2; ++ni)
          outp[(size_t)rloc * HID + wc + ni * 16 + lr] = acc[mi][ni][r];
      }
    }
  }
}

extern "C" void kernel_launch(void* const* d_in, const int* in_sizes, int n_in,
                              void* d_out, int out_size, void* d_ws, size_t ws_size,
                              hipStream_t stream) {
  const float* x = (const float*)d_in[0];
  const float* wg = (const float*)d_in[1];
  const float* wu = (const float*)d_in[2];
  const float* wd = (const float*)d_in[3];
  const int* gsz = (const int*)d_in[4];
  float* out = (float*)d_out;

  const int T = in_sizes[0] / HID;
  const int mtiles = (T + BM - 1) / BM;
  dim3 blk(256, 1, 1);

  // ws layout (path A): xbf | act | wgt | wut | wdt
  const size_t XBF = (size_t)T * HID;            // shorts
  const size_t ACT = (size_t)T * INTER;
  const size_t WT = (size_t)NE * HID * INTER;
  const size_t NEED = (XBF + ACT + 3 * WT) * sizeof(short);

  if (ws_size >= NEED) {
    short* xbf = (short*)d_ws;
    short* act = xbf + XBF;
    short* wgt = act + ACT;
    short* wut = wgt + WT;
    short* wdt = wut + WT;

    convert_x_kernel<<<(T * HID) / (256 * 8), blk, 0, stream>>>(x, xbf, T * HID);
    transpose_convert_kernel<<<dim3(INTER / 64, HID / 64, NE), blk, 0, stream>>>(wg, wgt, HID, INTER);
    transpose_convert_kernel<<<dim3(INTER / 64, HID / 64, NE), blk, 0, stream>>>(wu, wut, HID, INTER);
    transpose_convert_kernel<<<dim3(HID / 64, INTER / 64, NE), blk, 0, stream>>>(wd, wdt, INTER, HID);

    gate_up_bf_kernel<<<dim3(INTER / BN, mtiles, NE), blk, 0, stream>>>(xbf, wgt, wut, gsz, act);
    down_bf_kernel<<<dim3(HID / BN, mtiles, NE), blk, 0, stream>>>(act, wdt, gsz, out);
  } else {
    short* act = (short*)d_ws;  // 16 MB
    gate_up_kernel<<<dim3(INTER / BN, mtiles, NE), blk, 0, stream>>>(x, wg, wu, gsz, act);
    down_kernel<<<dim3(HID / BN, mtiles, NE), blk, 0, stream>>>(act, wd, gsz, out);
  }
}